// Round 1
// 755.115 us; speedup vs baseline: 1.0204x; 1.0204x over previous
//
#include <hip/hip_runtime.h>
#include <math.h>

// Problem constants (MahaClassifier): x[B,D], weight[C,D], weight2[D,D]
#define BN 4096
#define CN 32768
#define DN 2048
constexpr float EPS = 1e-12f;

// Native clang vector for nontemporal builtins (HIP float4 is a struct).
typedef float f4 __attribute__((ext_vector_type(4)));

// ---------------------------------------------------------------- k0: zero
__global__ void k0_zero(float* __restrict__ p, int n) {
    int i = blockIdx.x * blockDim.x + threadIdx.x;
    if (i < n) p[i] = 0.0f;
}

// ------------------------------------------- k1: colnorm2[k] = sum_r w2[r,k]^2
// grid: (DN/1024, DN/16) = (2,128), block 256. Each thread owns 4 consecutive
// columns (float4) for a 16-row chunk, then one atomicAdd per column.
__global__ void k1_colnorm(const float* __restrict__ w2, float* __restrict__ colnorm2) {
    int col = blockIdx.x * 1024 + threadIdx.x * 4;
    int r0  = blockIdx.y * 16;
    float4 acc = make_float4(0.f, 0.f, 0.f, 0.f);
    #pragma unroll
    for (int r = 0; r < 16; ++r) {
        const float4 w = *reinterpret_cast<const float4*>(w2 + (size_t)(r0 + r) * DN + col);
        acc.x += w.x * w.x; acc.y += w.y * w.y;
        acc.z += w.z * w.z; acc.w += w.w * w.w;
    }
    atomicAdd(&colnorm2[col + 0], acc.x);
    atomicAdd(&colnorm2[col + 1], acc.y);
    atomicAdd(&colnorm2[col + 2], acc.z);
    atomicAdd(&colnorm2[col + 3], acc.w);
}

// --------------------------------- k2: s[j] = sum_k w2[j,k] / max(colnorm[k],eps)
// One wave (64 lanes) per row, 4 rows/block. inv[] staged in LDS; read as
// float4 (ds_read_b128, conflict-free) instead of 4x b32 (8-way conflict).
__global__ void k2_rowsum(const float* __restrict__ w2, const float* __restrict__ colnorm2,
                          float* __restrict__ s) {
    __shared__ __align__(16) float inv[DN];
    for (int i = threadIdx.x; i < DN; i += 256)
        inv[i] = 1.0f / fmaxf(sqrtf(colnorm2[i]), EPS);
    __syncthreads();

    int wave = threadIdx.x >> 6;
    int lane = threadIdx.x & 63;
    int j = blockIdx.x * 4 + wave;
    const float* row = w2 + (size_t)j * DN;
    float acc = 0.0f;
    #pragma unroll
    for (int it = 0; it < DN / 256; ++it) {
        int k = it * 256 + lane * 4;
        float4 w = *reinterpret_cast<const float4*>(row + k);
        float4 iv = *reinterpret_cast<const float4*>(&inv[k]);
        acc += w.x * iv.x + w.y * iv.y + w.z * iv.z + w.w * iv.w;
    }
    #pragma unroll
    for (int off = 32; off > 0; off >>= 1) acc += __shfl_down(acc, off, 64);
    if (lane == 0) s[j] = acc;
}

// ---------------- k3: xs[i] = (x_i . s)/||x_i||  and  ms[c] = (w_c . s)/||w_c||
// One wave per 4 consecutive rows of the concatenated (B + C) row space.
// s is held entirely in registers (8 float4/lane) -- no LDS, no bank
// conflicts, loaded once per wave instead of once per row.
#define K3_RPW 4
__global__ void k3_dots(const float* __restrict__ x, const float* __restrict__ w,
                        const float* __restrict__ s,
                        float* __restrict__ xs, float* __restrict__ ms) {
    int wave = threadIdx.x >> 6;
    int lane = threadIdx.x & 63;
    int wid  = blockIdx.x * 4 + wave;   // global wave id
    int r0   = wid * K3_RPW;

    // lane-private fragment of s: element k = it*256 + lane*4 (+0..3)
    float4 sv[DN / 256];
    #pragma unroll
    for (int it = 0; it < DN / 256; ++it)
        sv[it] = *reinterpret_cast<const float4*>(s + it * 256 + lane * 4);

    for (int rr = 0; rr < K3_RPW; ++rr) {
        int r = r0 + rr;
        const float* row;
        if (r < BN) row = x + (size_t)r * DN;
        else        row = w + (size_t)(r - BN) * DN;

        float acc = 0.0f, n2 = 0.0f;
        #pragma unroll
        for (int it = 0; it < DN / 256; ++it) {
            float4 v = *reinterpret_cast<const float4*>(row + it * 256 + lane * 4);
            acc += v.x * sv[it].x + v.y * sv[it].y + v.z * sv[it].z + v.w * sv[it].w;
            n2  += v.x * v.x + v.y * v.y + v.z * v.z + v.w * v.w;
        }
        #pragma unroll
        for (int off = 32; off > 0; off >>= 1) {
            acc += __shfl_down(acc, off, 64);
            n2  += __shfl_down(n2, off, 64);
        }
        if (lane == 0) {
            float val = acc / fmaxf(sqrtf(n2), EPS);
            if (r < BN) xs[r] = val; else ms[r - BN] = val;
        }
    }
}

// --------------------------------------------- k4: out[i,c] = ms[c] - xs[i]
// Each thread owns 4 columns (ms fragment in registers) and loops 32 rows:
// 32x fewer blocks, ms read once per 32 rows instead of per row, and
// nontemporal stores (out is write-once, never re-read).
#define K4_ROWS 32
__global__ void k4_write(const float* __restrict__ xs, const float* __restrict__ ms,
                         float* __restrict__ out) {
    int c  = blockIdx.x * 1024 + threadIdx.x * 4;
    int i0 = blockIdx.y * K4_ROWS;
    f4 m = *reinterpret_cast<const f4*>(ms + c);
    #pragma unroll
    for (int r = 0; r < K4_ROWS; ++r) {
        float xv = xs[i0 + r];               // block-uniform -> scalar load
        f4 v = m - xv;
        __builtin_nontemporal_store(v, reinterpret_cast<f4*>(out + (size_t)(i0 + r) * CN + c));
    }
}

extern "C" void kernel_launch(void* const* d_in, const int* in_sizes, int n_in,
                              void* d_out, int out_size, void* d_ws, size_t ws_size,
                              hipStream_t stream) {
    const float* x  = (const float*)d_in[0];   // [B, D]
    const float* w  = (const float*)d_in[1];   // [C, D]
    const float* w2 = (const float*)d_in[2];   // [D, D]
    float* out = (float*)d_out;                // [B, C]

    // Workspace layout (floats): colnorm2[D] | s[D] | xs[B] | ms[C]
    float* colnorm2 = (float*)d_ws;
    float* s  = colnorm2 + DN;
    float* xs = s + DN;
    float* ms = xs + BN;

    k0_zero<<<(DN + 255) / 256, 256, 0, stream>>>(colnorm2, DN);
    k1_colnorm<<<dim3(DN / 1024, DN / 16), 256, 0, stream>>>(w2, colnorm2);
    k2_rowsum<<<DN / 4, 256, 0, stream>>>(w2, colnorm2, s);
    k3_dots<<<(BN + CN) / (4 * K3_RPW), 256, 0, stream>>>(x, w, s, xs, ms);
    k4_write<<<dim3(CN / 1024, BN / K4_ROWS), 256, 0, stream>>>(xs, ms, out);
}